// Round 11
// baseline (180.154 us; speedup 1.0000x reference)
//
#include <hip/hip_runtime.h>

using bf16 = __bf16;
typedef __bf16 bf16x8 __attribute__((ext_vector_type(8)));
typedef __bf16 bf16x4 __attribute__((ext_vector_type(4)));
typedef float  f32x4  __attribute__((ext_vector_type(4)));

#define MFMA16(a, b, c) __builtin_amdgcn_mfma_f32_16x16x32_bf16((a), (b), (c), 0, 0, 0)

static constexpr int S = 2048, E = 1024;
static constexpr float CSCALE = 0.18033688011112042f;  // 1/sqrt(64) * log2(e)

__device__ __forceinline__ void gld16(const bf16* g, bf16* l) {
    __builtin_amdgcn_global_load_lds((const __attribute__((address_space(1))) unsigned*)g,
                                     (__attribute__((address_space(3))) unsigned*)l, 16, 0, 0);
}

// ---------------- fused prep: cvt(hs) + transpose-cvt(w0,w1) with 64x32 tiles ----------------
// Transpose tiles are 64(k) x 32(n): reads 128B/wave-row, writes 64 consecutive bf16 = 128B/wave-row.
__global__ __launch_bounds__(256) void k_prep(const float* __restrict__ hs, const float* __restrict__ w0,
                                              const float* __restrict__ w1, bf16* __restrict__ A0,
                                              bf16* __restrict__ Wt0, bf16* __restrict__ Wt1) {
    __shared__ float tile[64][33];
    const int bx = blockIdx.x;
    if (bx < 4096) {
        int i = (bx * 256 + threadIdx.x) * 4;
        float4 v = *(const float4*)(hs + i);
        bf16x4 o = { (bf16)v.x, (bf16)v.y, (bf16)v.z, (bf16)v.w };
        *(bf16x4*)(A0 + i) = o;
        return;
    }
    const float* in;
    bf16* outp;
    int K, N, nb, kb;
    const int j = bx - 4096;
    if (j < 1536) { in = w0; outp = Wt0; K = 1024; N = 3072; nb = j % 96; kb = j / 96; }
    else          { in = w1; outp = Wt1; K = 1024; N = 1024; nb = (j - 1536) % 32; kb = (j - 1536) / 32; }
    const int bxx = nb * 32, byy = kb * 64;
    {
        const int r0 = threadIdx.x >> 5, c = threadIdx.x & 31;
#pragma unroll
        for (int i = 0; i < 8; i++)
            tile[r0 + i * 8][c] = in[(long)(byy + r0 + i * 8) * N + bxx + c];
    }
    __syncthreads();
    {
        const int n0 = threadIdx.x >> 6, k = threadIdx.x & 63;
#pragma unroll
        for (int i = 0; i < 8; i++) {
            const int n = n0 + i * 4;
            outp[(long)(bxx + n) * K + byy + k] = (bf16)tile[k][n];
        }
    }
}

// ---------------- QKV GEMM, BK=64, XOR-swizzled LDS; Q row-major, K/V fragment-linear ----------------
__global__ __launch_bounds__(256) void k_gemm_qkv(const bf16* __restrict__ A, const bf16* __restrict__ Bt,
                                                  const float* __restrict__ bias, bf16* __restrict__ Qs,
                                                  bf16* __restrict__ Kf, bf16* __restrict__ Vf, int Kk) {
    const int bm = blockIdx.x * 128;
    const int bn = blockIdx.y * 128;
    const int tid = threadIdx.x;
    const int w = tid >> 6, lane = tid & 63;
    const int wm = (w >> 1) * 64, wn = (w & 1) * 64;
    const int col = lane & 15, quad = lane >> 4;

    __shared__ __align__(16) char smem[32768];
    bf16* sA = (bf16*)smem;                 // 128 x 64 (swizzled)
    bf16* sB = (bf16*)(smem + 16384);       // 128 x 64 (swizzled)
    bf16* T  = (bf16*)smem;                 // epilogue repack (after barrier)

    const bf16* pA[4]; const bf16* pB[4]; bf16* lA[4]; bf16* lB[4];
#pragma unroll
    for (int i = 0; i < 4; i++) {
        const int c = i * 256 + w * 64 + lane;
        const int r = c >> 3, sl = (c & 7) ^ (r & 7);
        pA[i] = A  + (long)(bm + r) * Kk + sl * 8;
        pB[i] = Bt + (long)(bn + r) * Kk + sl * 8;
        lA[i] = sA + i * 2048 + w * 512;
        lB[i] = sB + i * 2048 + w * 512;
    }

    f32x4 acc[4][4] = {};

    for (int k0 = 0; k0 < Kk; k0 += 64) {
        __syncthreads();
#pragma unroll
        for (int i = 0; i < 4; i++) gld16(pA[i] + k0, lA[i]);
#pragma unroll
        for (int i = 0; i < 4; i++) gld16(pB[i] + k0, lB[i]);
        __syncthreads();
#pragma unroll
        for (int h = 0; h < 2; h++) {
            bf16x8 af[4], bfr[4];
#pragma unroll
            for (int mt = 0; mt < 4; mt++) {
                const int row = wm + mt * 16 + col;
                af[mt] = *(const bf16x8*)(sA + row * 64 + (((h * 4 + quad) ^ (col & 7)) * 8));
            }
#pragma unroll
            for (int nt = 0; nt < 4; nt++) {
                const int row = wn + nt * 16 + col;
                bfr[nt] = *(const bf16x8*)(sB + row * 64 + (((h * 4 + quad) ^ (col & 7)) * 8));
            }
#pragma unroll
            for (int mt = 0; mt < 4; mt++)
#pragma unroll
                for (int nt = 0; nt < 4; nt++)
                    acc[mt][nt] = MFMA16(af[mt], bfr[nt], acc[mt][nt]);
        }
    }

    const int seg = bn >> 10;  // 0: Q, 1: K, 2: V
    const int b = bm >> 11;
    const int kt0 = (bm & 2047) >> 6;

    if (seg == 0) {
#pragma unroll
        for (int mt = 0; mt < 4; mt++) {
            const int gr = bm + wm + mt * 16 + quad * 4;
#pragma unroll
            for (int nt = 0; nt < 4; nt++) {
                const int gc = bn + wn + nt * 16 + col;
                const float bv = bias[gc];
#pragma unroll
                for (int r = 0; r < 4; r++)
                    Qs[(long)(gr + r) * 1024 + gc] = (bf16)((acc[mt][nt][r] + bv) * CSCALE);
            }
        }
        return;
    }

    const int hl = w >> 1;
    if (seg == 1) {
        const int bh = b * 16 + (bn >> 6) - 16 + hl;
#pragma unroll 1
        for (int p = 0; p < 2; p++) {
            __syncthreads();
            if ((wm >> 6) == p) {
#pragma unroll
                for (int mt = 0; mt < 4; mt++) {
                    const int sl = mt * 16 + quad * 4;
#pragma unroll
                    for (int nt = 0; nt < 4; nt++) {
                        const int gcl = wn + nt * 16 + col;
                        const float bv = bias[bn + gcl];
#pragma unroll
                        for (int r = 0; r < 4; r++)
                            T[(sl + r) * 136 + gcl] = (bf16)(acc[mt][nt][r] + bv);
                    }
                }
            }
            __syncthreads();
            const int ktp = kt0 + p;
#pragma unroll
            for (int mi = 0; mi < 2; mi++) {
                const int mt = (w & 1) * 2 + mi;
#pragma unroll
                for (int half = 0; half < 2; half++) {
                    bf16x8 ch = *(const bf16x8*)(T + (mt * 16 + col) * 136 + hl * 64 + half * 32 + quad * 8);
                    const long chunk = ((long)(bh * 32 + ktp) * 8 + mt * 2 + half) * 64 + lane;
                    *(bf16x8*)(Kf + chunk * 8) = ch;
                }
            }
        }
    } else {
        const int bh = b * 16 + (bn >> 6) - 32 + hl;
#pragma unroll 1
        for (int p = 0; p < 2; p++) {
            __syncthreads();
            if ((wm >> 6) == p) {
#pragma unroll
                for (int mt = 0; mt < 4; mt++) {
                    const int sl = mt * 16 + quad * 4;
#pragma unroll
                    for (int nt = 0; nt < 4; nt++) {
                        const int gcl = wn + nt * 16 + col;
                        const float bv = bias[bn + gcl];
                        bf16x4 pk = { (bf16)(acc[mt][nt][0] + bv), (bf16)(acc[mt][nt][1] + bv),
                                      (bf16)(acc[mt][nt][2] + bv), (bf16)(acc[mt][nt][3] + bv) };
                        *(bf16x4*)(T + gcl * 72 + sl) = pk;
                    }
                }
            }
            __syncthreads();
            const int ktp = kt0 + p;
#pragma unroll
            for (int di = 0; di < 2; di++) {
                const int dt = (w & 1) * 2 + di;
#pragma unroll
                for (int ks = 0; ks < 2; ks++) {
                    bf16x8 ch = *(const bf16x8*)(T + (hl * 64 + dt * 16 + col) * 72 + ks * 32 + quad * 8);
                    const long chunk = ((long)(bh * 32 + ktp) * 8 + dt * 2 + ks) * 64 + lane;
                    *(bf16x8*)(Vf + chunk * 8) = ch;
                }
            }
        }
    }
}

// ---------------- bf16 GEMM 64x128 tile, BK=64, XOR-swizzled (proj) ----------------
__global__ __launch_bounds__(256) void k_gemm_bt64(const bf16* __restrict__ A, const bf16* __restrict__ Bt,
                                                    const float* __restrict__ bias, float* __restrict__ Cout,
                                                    int Mm, int Nn, int Kk) {
    const int bm = blockIdx.x * 64;
    const int bn = blockIdx.y * 128;
    const int tid = threadIdx.x;
    const int w = tid >> 6, lane = tid & 63;
    const int wm = (w >> 1) * 32, wn = (w & 1) * 64;
    const int col = lane & 15, quad = lane >> 4;

    __shared__ bf16 sA[64 * 64];
    __shared__ bf16 sB[128 * 64];

    const bf16* pA[2]; bf16* lA[2];
#pragma unroll
    for (int i = 0; i < 2; i++) {
        const int c = i * 256 + w * 64 + lane;
        const int r = c >> 3, sl = (c & 7) ^ (r & 7);
        pA[i] = A + (long)(bm + r) * Kk + sl * 8;
        lA[i] = sA + i * 2048 + w * 512;
    }
    const bf16* pB[4]; bf16* lB[4];
#pragma unroll
    for (int i = 0; i < 4; i++) {
        const int c = i * 256 + w * 64 + lane;
        const int r = c >> 3, sl = (c & 7) ^ (r & 7);
        pB[i] = Bt + (long)(bn + r) * Kk + sl * 8;
        lB[i] = sB + i * 2048 + w * 512;
    }

    f32x4 acc[2][4] = {};

    for (int k0 = 0; k0 < Kk; k0 += 64) {
        __syncthreads();
#pragma unroll
        for (int i = 0; i < 2; i++) gld16(pA[i] + k0, lA[i]);
#pragma unroll
        for (int i = 0; i < 4; i++) gld16(pB[i] + k0, lB[i]);
        __syncthreads();
#pragma unroll
        for (int h = 0; h < 2; h++) {
            bf16x8 af[2], bfr[4];
#pragma unroll
            for (int mt = 0; mt < 2; mt++) {
                const int row = wm + mt * 16 + col;
                af[mt] = *(const bf16x8*)(sA + row * 64 + (((h * 4 + quad) ^ (col & 7)) * 8));
            }
#pragma unroll
            for (int nt = 0; nt < 4; nt++) {
                const int row = wn + nt * 16 + col;
                bfr[nt] = *(const bf16x8*)(sB + row * 64 + (((h * 4 + quad) ^ (col & 7)) * 8));
            }
#pragma unroll
            for (int mt = 0; mt < 2; mt++)
#pragma unroll
                for (int nt = 0; nt < 4; nt++)
                    acc[mt][nt] = MFMA16(af[mt], bfr[nt], acc[mt][nt]);
        }
    }

#pragma unroll
    for (int mt = 0; mt < 2; mt++) {
        const int gr = bm + wm + mt * 16 + quad * 4;
#pragma unroll
        for (int nt = 0; nt < 4; nt++) {
            const int gc = bn + wn + nt * 16 + col;
            const float bv = bias[gc];
#pragma unroll
            for (int r = 0; r < 4; r++)
                Cout[(long)(gr + r) * Nn + gc] = acc[mt][nt][r] + bv;
        }
    }
}

// ---------------- causal flash attention: one tile/block, kt-split waves, 4 waves/SIMD ----------------
// 2048 blocks x 128 thr (2 waves), heavy tiles first. Wave 0 = lower kt half, wave 1 = upper half
// (incl. diagonal mask). Flash-decode merge via LDS, one barrier. LDS 18.4KB -> 8 blocks/CU.
__global__ __launch_bounds__(128) void k_attn(const bf16* __restrict__ Qs, const bf16* __restrict__ Kf,
                                              const bf16* __restrict__ Vf, bf16* __restrict__ out) {
    const int bh = blockIdx.x & 31;
    const int t = 63 - (blockIdx.x >> 5);     // heavy tiles launch first
    const int b = bh >> 4, h = bh & 15;
    const int tid = threadIdx.x;
    const int w = tid >> 6, lane = tid & 63;
    const int col = lane & 15, quad = lane >> 4;
    const int q0 = t * 32;
    const int nkt = (t >> 1) + 1;
    const int kA = nkt >> 1;
    const int kbeg = w ? kA : 0;
    const int kend = w ? nkt : kA;

    __shared__ bf16 sP[2][32 * 72];
    __shared__ float M[64][36];               // [lane][0..31 O | 32 m0 33 l0 34 m1 35 l1]
    bf16* pw = sP[w];

    const bf16* kfb = Kf + ((long)bh << 17) + lane * 8;
    const bf16* vfb = Vf + ((long)bh << 17) + lane * 8;

    bf16x8 bq[2][2];
#pragma unroll
    for (int qg = 0; qg < 2; qg++) {
        const bf16* qp = Qs + (long)(b * S + q0 + qg * 16 + col) * E + h * 64 + quad * 8;
        bq[qg][0] = *(const bf16x8*)(qp);
        bq[qg][1] = *(const bf16x8*)(qp + 32);
    }
    float m_[2] = { -1e30f, -1e30f }, l_[2] = { 0.f, 0.f };
    f32x4 o[2][4] = {};

#pragma unroll 1
    for (int kt = kbeg; kt < kend; kt++) {
        bf16x8 kfr[4][2], vfr[4][2];
#pragma unroll
        for (int mt = 0; mt < 4; mt++)
#pragma unroll
            for (int half = 0; half < 2; half++)
                kfr[mt][half] = *(const bf16x8*)(kfb + ((long)(kt * 8 + mt * 2 + half) << 9));
#pragma unroll
        for (int dt = 0; dt < 4; dt++)
#pragma unroll
            for (int ks = 0; ks < 2; ks++)
                vfr[dt][ks] = *(const bf16x8*)(vfb + ((long)(kt * 8 + dt * 2 + ks) << 9));

        f32x4 s[2][4];
#pragma unroll
        for (int mt = 0; mt < 4; mt++)
#pragma unroll
            for (int qg = 0; qg < 2; qg++) {
                f32x4 z = {};
                z = MFMA16(kfr[mt][0], bq[qg][0], z);
                z = MFMA16(kfr[mt][1], bq[qg][1], z);
                s[qg][mt] = z;
            }
        if (kt == nkt - 1) {  // diagonal tile (always in wave 1's range)
#pragma unroll
            for (int qg = 0; qg < 2; qg++) {
                const int qrow = q0 + qg * 16 + col;
#pragma unroll
                for (int mt = 0; mt < 4; mt++)
#pragma unroll
                    for (int r = 0; r < 4; r++)
                        if (kt * 64 + mt * 16 + quad * 4 + r > qrow) s[qg][mt][r] = -1e30f;
            }
        }
#pragma unroll
        for (int qg = 0; qg < 2; qg++) {
            float cm = -1e30f;
#pragma unroll
            for (int mt = 0; mt < 4; mt++)
#pragma unroll
                for (int r = 0; r < 4; r++) cm = fmaxf(cm, s[qg][mt][r]);
            cm = fmaxf(cm, __shfl_xor(cm, 16));
            cm = fmaxf(cm, __shfl_xor(cm, 32));
            const float mnew = fmaxf(m_[qg], cm);
            const float alpha = __builtin_amdgcn_exp2f(m_[qg] - mnew);
            m_[qg] = mnew;
            float rs = 0.f;
#pragma unroll
            for (int mt = 0; mt < 4; mt++)
#pragma unroll
                for (int r = 0; r < 4; r++) {
                    float pe = __builtin_amdgcn_exp2f(s[qg][mt][r] - mnew);
                    s[qg][mt][r] = pe;
                    rs += pe;
                }
            l_[qg] = l_[qg] * alpha + rs;
#pragma unroll
            for (int dt = 0; dt < 4; dt++)
#pragma unroll
                for (int r = 0; r < 4; r++) o[qg][dt][r] *= alpha;
#pragma unroll
            for (int mt = 0; mt < 4; mt++) {
                bf16x4 pk = { (bf16)s[qg][mt][0], (bf16)s[qg][mt][1],
                              (bf16)s[qg][mt][2], (bf16)s[qg][mt][3] };
                *(bf16x4*)(pw + (qg * 16 + col) * 72 + mt * 16 + quad * 4) = pk;
            }
        }
#pragma unroll
        for (int ks = 0; ks < 2; ks++) {
            bf16x8 ap[2];
#pragma unroll
            for (int qg = 0; qg < 2; qg++)
                ap[qg] = *(const bf16x8*)(pw + (qg * 16 + col) * 72 + ks * 32 + quad * 8);
#pragma unroll
            for (int dt = 0; dt < 4; dt++)
#pragma unroll
                for (int qg = 0; qg < 2; qg++)
                    o[qg][dt] = MFMA16(vfr[dt][ks], ap[qg], o[qg][dt]);
        }
    }

    // finish per-lane l reduction -> replicated row sums
#pragma unroll
    for (int qg = 0; qg < 2; qg++) {
        float lt = l_[qg];
        lt += __shfl_xor(lt, 16);
        lt += __shfl_xor(lt, 32);
        l_[qg] = lt;
    }

    if (w == 0) {  // publish lower-half partials
#pragma unroll
        for (int qg = 0; qg < 2; qg++) {
#pragma unroll
            for (int dt = 0; dt < 4; dt++)
                *(f32x4*)&M[lane][qg * 16 + dt * 4] = o[qg][dt];
            M[lane][32 + qg * 2] = m_[qg];
            M[lane][33 + qg * 2] = l_[qg];
        }
    }
    __syncthreads();
    if (w == 1) {  // merge + output
#pragma unroll
        for (int qg = 0; qg < 2; qg++) {
            const float m0 = M[lane][32 + qg * 2];
            const float l0 = M[lane][33 + qg * 2];
            const float mm = fmaxf(m0, m_[qg]);
            const float a0 = __builtin_amdgcn_exp2f(m0 - mm);
            const float a1 = __builtin_amdgcn_exp2f(m_[qg] - mm);
            const float li = 1.f / (l0 * a0 + l_[qg] * a1);
            bf16* op = out + (long)(b * S + q0 + qg * 16 + col) * E + h * 64 + quad * 4;
#pragma unroll
            for (int dt = 0; dt < 4; dt++) {
                f32x4 o0 = *(const f32x4*)&M[lane][qg * 16 + dt * 4];
                bf16x4 ov;
#pragma unroll
                for (int r = 0; r < 4; r++)
                    ov[r] = (bf16)((o0[r] * a0 + o[qg][dt][r] * a1) * li);
                *(bf16x4*)(op + dt * 16) = ov;
            }
        }
    }
}

extern "C" void kernel_launch(void* const* d_in, const int* in_sizes, int n_in,
                              void* d_out, int out_size, void* d_ws, size_t ws_size,
                              hipStream_t stream) {
    const float* hs = (const float*)d_in[0];   // [2,2048,1024]
    const float* w0 = (const float*)d_in[1];   // [1024,3072]
    const float* b0 = (const float*)d_in[2];   // [3072]
    const float* w1 = (const float*)d_in[3];   // [1024,1024]
    const float* b1 = (const float*)d_in[4];   // [1024]
    float* outp = (float*)d_out;               // [2,2048,1024] fp32

    char* ws = (char*)d_ws;
    bf16* A0    = (bf16*)(ws);                   // 8 MB
    bf16* Wt0   = (bf16*)(ws + 8388608);         // 6 MB
    bf16* Wt1   = (bf16*)(ws + 14680064);        // 2 MB
    bf16* Qs    = (bf16*)(ws + 16777216);        // 8 MB  [4096][1024] scaled Q
    bf16* Kf    = (bf16*)(ws + 25165824);        // 8 MB  fragment-linear K
    bf16* Vf    = (bf16*)(ws + 33554432);        // 8 MB  fragment-linear V^T
    bf16* attnO = (bf16*)(ws + 41943040);        // 8 MB

    k_prep<<<6144, 256, 0, stream>>>(hs, w0, w1, A0, Wt0, Wt1);
    k_gemm_qkv<<<dim3(32, 24), 256, 0, stream>>>(A0, Wt0, b0, Qs, Kf, Vf, 1024);
    k_attn<<<2048, 128, 0, stream>>>(Qs, Kf, Vf, attnO);
    k_gemm_bt64<<<dim3(64, 8), 256, 0, stream>>>(attnO, Wt1, b1, outp, 4096, 1024, 1024);
}